// Round 4
// baseline (243.039 us; speedup 1.0000x reference)
//
#include <hip/hip_runtime.h>
#include <math.h>

// HoltWintersDecomposition: x (8192, 2048) f32, sequential per-row recurrence.
// Structural limit: 8192 rows = 128 wave64 max -> occupancy can't hide latency.
// Fix: ILP instead of TLP -- each lane runs TWO independent rows, interleaved,
// so the two dependent chains fill each other's latency bubbles.
// 256 blocks x 16 lanes x 2 rows/lane = 8192 rows, all 256 CUs active,
// same per-CU memory footprint as the round-2 140us kernel (32 rows/CU).
// Direct per-lane float4 loads/stores (LDS transpose regressed: ds_read latency
// with 1 wave and no TLP costs more than store line-fragmentation saves).

constexpr int   T    = 2048;
constexpr int   B    = 8192;
constexpr int   CH   = 16;        // steps per chunk (one 64B line of x)
constexpr int   NCH  = T / CH;    // 128 chunks
constexpr int   LPB  = 16;        // lanes per block
constexpr int   RPB  = 32;        // rows per block (2 per lane)
constexpr float EPS  = 1e-8f;

__device__ __forceinline__ float rcp_nr(float d) {
    float r = __builtin_amdgcn_rcpf(d);
    float e = __builtin_fmaf(-d, r, 1.0f);   // e = 1 - d*r
    return __builtin_fmaf(r, e, r);          // ~1 ulp
}

__global__ __launch_bounds__(LPB, 1)
void hw_kernel(const float* __restrict__ x,
               const float* __restrict__ pla,
               const float* __restrict__ plg,
               float* __restrict__ out)
{
    const int lane = threadIdx.x;                  // 0..15
    const int r0   = blockIdx.x * RPB + 2 * lane;  // even row
    const int r1   = r0 + 1;                       // odd row

    const float alpha = 1.0f / (1.0f + expf(-pla[0]));
    const float gamma = 1.0f / (1.0f + expf(-plg[0]));
    const float oma = 1.0f - alpha;
    const float omg = 1.0f - gamma;

    const float* __restrict__ x0 = x + (size_t)r0 * T;
    const float* __restrict__ x1 = x + (size_t)r1 * T;
    float* __restrict__ l0 = out + (size_t)r0 * T;
    float* __restrict__ s0 = out + (size_t)(B + r0) * T;
    float* __restrict__ y0 = out + (size_t)(2 * B + r0) * T;
    float* __restrict__ l1 = out + (size_t)r1 * T;
    float* __restrict__ s1 = out + (size_t)(B + r1) * T;
    float* __restrict__ y1 = out + (size_t)(2 * B + r1) * T;

    float lpA = 0.0f, spA = 1.0f;   // row0 carried state
    float lpB = 0.0f, spB = 1.0f;   // row1 carried state

    auto step = [&](float xt, float& lp, float& sp,
                    float& lo, float& so, float& yo) {
        const float rs = rcp_nr(sp + EPS);
        const float lt = __builtin_fmaf(alpha * xt, rs, oma * lp);
        const float rl = rcp_nr(lt + EPS);
        const float st = __builtin_fmaf(gamma * xt, rl, omg * sp);
        const float yt = xt * __builtin_amdgcn_rcpf(__builtin_fmaf(lt, st, EPS));
        lo = lt; so = st; yo = yt;
        lp = lt; sp = st;
    };

    float4 A0[4], A1[4], B0[4], B1[4];   // x double-buffer, both rows

    auto loadA = [&](int c) {
        const float* p0 = x0 + c * CH;
        const float* p1 = x1 + c * CH;
        #pragma unroll
        for (int k = 0; k < 4; ++k) {
            A0[k] = *reinterpret_cast<const float4*>(p0 + 4 * k);
            A1[k] = *reinterpret_cast<const float4*>(p1 + 4 * k);
        }
    };
    auto loadB = [&](int c) {
        const float* p0 = x0 + c * CH;
        const float* p1 = x1 + c * CH;
        #pragma unroll
        for (int k = 0; k < 4; ++k) {
            B0[k] = *reinterpret_cast<const float4*>(p0 + 4 * k);
            B1[k] = *reinterpret_cast<const float4*>(p1 + 4 * k);
        }
    };

    // one 16-step chunk for both rows; xbuf0/xbuf1 are 4xfloat4 register tiles
    auto chunk_pair = [&](const float4* xb0, const float4* xb1,
                          bool first, int t0) {
        #pragma unroll
        for (int q = 0; q < 4; ++q) {
            const float4 a = xb0[q];
            const float4 b = xb1[q];
            float4 lv0, sv0, yv0, lv1, sv1, yv1;
            if (first && q == 0) {
                // t == 0: l0 = x0, s0 = 1, y0 = x0/(x0+eps) -- both rows
                lpA = a.x; spA = 1.0f;
                lv0.x = a.x; sv0.x = 1.0f;
                yv0.x = a.x * __builtin_amdgcn_rcpf(a.x + EPS);
                lpB = b.x; spB = 1.0f;
                lv1.x = b.x; sv1.x = 1.0f;
                yv1.x = b.x * __builtin_amdgcn_rcpf(b.x + EPS);
                step(a.y, lpA, spA, lv0.y, sv0.y, yv0.y);
                step(b.y, lpB, spB, lv1.y, sv1.y, yv1.y);
                step(a.z, lpA, spA, lv0.z, sv0.z, yv0.z);
                step(b.z, lpB, spB, lv1.z, sv1.z, yv1.z);
                step(a.w, lpA, spA, lv0.w, sv0.w, yv0.w);
                step(b.w, lpB, spB, lv1.w, sv1.w, yv1.w);
            } else {
                step(a.x, lpA, spA, lv0.x, sv0.x, yv0.x);
                step(b.x, lpB, spB, lv1.x, sv1.x, yv1.x);
                step(a.y, lpA, spA, lv0.y, sv0.y, yv0.y);
                step(b.y, lpB, spB, lv1.y, sv1.y, yv1.y);
                step(a.z, lpA, spA, lv0.z, sv0.z, yv0.z);
                step(b.z, lpB, spB, lv1.z, sv1.z, yv1.z);
                step(a.w, lpA, spA, lv0.w, sv0.w, yv0.w);
                step(b.w, lpB, spB, lv1.w, sv1.w, yv1.w);
            }
            const int t = t0 + 4 * q;
            *reinterpret_cast<float4*>(l0 + t) = lv0;
            *reinterpret_cast<float4*>(s0 + t) = sv0;
            *reinterpret_cast<float4*>(y0 + t) = yv0;
            *reinterpret_cast<float4*>(l1 + t) = lv1;
            *reinterpret_cast<float4*>(s1 + t) = sv1;
            *reinterpret_cast<float4*>(y1 + t) = yv1;
        }
    };

    // prologue: chunks 0,1 in flight; peel chunk 0 (t==0), refill A with chunk 2
    loadA(0);
    loadB(1);
    chunk_pair(A0, A1, true, 0);
    loadA(2);

    // steady state: consume B then A; loads stay 1 chunk (~1100 cy) ahead
    #pragma unroll 1
    for (int c = 1; c < NCH - 1; c += 2) {
        chunk_pair(B0, B1, false, c * CH);
        loadB((c + 2 < NCH) ? c + 2 : NCH - 1);
        chunk_pair(A0, A1, false, (c + 1) * CH);
        loadA((c + 3 < NCH) ? c + 3 : NCH - 1);
    }

    // tail: chunk 127 sits in B
    chunk_pair(B0, B1, false, (NCH - 1) * CH);
}

extern "C" void kernel_launch(void* const* d_in, const int* in_sizes, int n_in,
                              void* d_out, int out_size, void* d_ws, size_t ws_size,
                              hipStream_t stream) {
    const float* x   = (const float*)d_in[0];
    const float* pla = (const float*)d_in[1];
    const float* plg = (const float*)d_in[2];
    float* out = (float*)d_out;

    dim3 grid(B / RPB);   // 256 blocks -> 1 per CU
    dim3 block(LPB);      // 16 lanes, 2 rows each
    hw_kernel<<<grid, block, 0, stream>>>(x, pla, plg, out);
}

// Round 5
// 147.857 us; speedup vs baseline: 1.6437x; 1.6437x over previous
//
#include <hip/hip_runtime.h>
#include <math.h>

// HoltWintersDecomposition: x (8192, 2048) f32, sequential per-row recurrence.
// Lesson r4: wave64 issue cost is independent of active lanes -> FULL waves.
// 128 blocks x 64 lanes, 1 row/lane (8192 rows = 128 full waves, the structural
// max). Chain-bound target: ~48 cy/step (add->rcp->NR->fma, twice).
// Outputs double-buffered in registers (A/B sets) so scattered stores retire
// ~2 chunks before their registers are rewritten -> no vmcnt stalls on chain.
// x prefetched 2 chunks ahead in an A/B register double-buffer.

constexpr int   T    = 2048;
constexpr int   B    = 8192;
constexpr int   CH   = 16;        // steps per chunk (= one 64B line of x per lane)
constexpr int   NCH  = T / CH;    // 128 chunks
constexpr float EPS  = 1e-8f;

__device__ __forceinline__ float rcp_nr(float d) {
    float r = __builtin_amdgcn_rcpf(d);
    float e = __builtin_fmaf(-d, r, 1.0f);   // e = 1 - d*r
    return __builtin_fmaf(r, e, r);          // ~0.5 ulp
}

__global__ __launch_bounds__(64, 1)
void hw_kernel(const float* __restrict__ x,
               const float* __restrict__ pla,
               const float* __restrict__ plg,
               float* __restrict__ out)
{
    const int lane = threadIdx.x;                 // 0..63
    const int row  = blockIdx.x * 64 + lane;

    const float alpha = 1.0f / (1.0f + expf(-pla[0]));
    const float gamma = 1.0f / (1.0f + expf(-plg[0]));
    const float oma = 1.0f - alpha;
    const float omg = 1.0f - gamma;

    const float* __restrict__ xrow = x + (size_t)row * T;
    float* __restrict__ lrow = out + (size_t)row * T;
    float* __restrict__ srow = out + (size_t)(B + row) * T;
    float* __restrict__ yrow = out + (size_t)(2 * B + row) * T;

    float lp = 0.0f, sp = 1.0f;

    auto step = [&](float xt, float& lo, float& so, float& yo) {
        const float rs = rcp_nr(sp + EPS);
        const float lt = __builtin_fmaf(alpha * xt, rs, oma * lp);
        const float rl = rcp_nr(lt + EPS);
        const float st = __builtin_fmaf(gamma * xt, rl, omg * sp);
        const float yt = xt * __builtin_amdgcn_rcpf(__builtin_fmaf(lt, st, EPS));
        lo = lt; so = st; yo = yt;
        lp = lt; sp = st;
    };

    float4 XA[4], XB[4];                       // x double-buffer
    float4 LA[4], SA[4], YA[4];                // output buffer, phase A
    float4 LB[4], SB[4], YB[4];                // output buffer, phase B

    auto load = [&](float4* Xb, int c) {
        const float* p = xrow + c * CH;
        #pragma unroll
        for (int k = 0; k < 4; ++k)
            Xb[k] = *reinterpret_cast<const float4*>(p + 4 * k);
    };

    auto computeChunk = [&](const float4* Xb, float4* L, float4* S, float4* Y,
                            bool first) {
        #pragma unroll
        for (int q = 0; q < 4; ++q) {
            const float4 xv = Xb[q];
            if (first && q == 0) {
                // t == 0: l0 = x0, s0 = 1, y0 = x0/(x0 + eps)
                lp = xv.x; sp = 1.0f;
                L[0].x = xv.x; S[0].x = 1.0f;
                Y[0].x = xv.x * __builtin_amdgcn_rcpf(xv.x + EPS);
                step(xv.y, L[0].y, S[0].y, Y[0].y);
                step(xv.z, L[0].z, S[0].z, Y[0].z);
                step(xv.w, L[0].w, S[0].w, Y[0].w);
            } else {
                step(xv.x, L[q].x, S[q].x, Y[q].x);
                step(xv.y, L[q].y, S[q].y, Y[q].y);
                step(xv.z, L[q].z, S[q].z, Y[q].z);
                step(xv.w, L[q].w, S[q].w, Y[q].w);
            }
        }
    };

    auto storeChunk = [&](const float4* L, const float4* S, const float4* Y,
                          int c) {
        const int t = c * CH;
        #pragma unroll
        for (int k = 0; k < 4; ++k) {
            *reinterpret_cast<float4*>(lrow + t + 4 * k) = L[k];
            *reinterpret_cast<float4*>(srow + t + 4 * k) = S[k];
            *reinterpret_cast<float4*>(yrow + t + 4 * k) = Y[k];
        }
    };

    // prologue: chunks 0,1 in flight; peel chunk 0 (t==0), refill A with chunk 2
    load(XA, 0);
    load(XB, 1);
    computeChunk(XA, LA, SA, YA, true);
    storeChunk(LA, SA, YA, 0);
    load(XA, 2);

    // steady state: B then A per iteration; x loads ~2 chunks ahead of use;
    // each output buffer is rewritten ~1 full chunk after its stores issue.
    #pragma unroll 1
    for (int c = 1; c < NCH - 1; c += 2) {
        computeChunk(XB, LB, SB, YB, false);
        storeChunk(LB, SB, YB, c);
        load(XB, (c + 2 < NCH) ? c + 2 : NCH - 1);

        computeChunk(XA, LA, SA, YA, false);
        storeChunk(LA, SA, YA, c + 1);
        load(XA, (c + 3 < NCH) ? c + 3 : NCH - 1);
    }

    // tail: chunk 127 sits in B
    computeChunk(XB, LB, SB, YB, false);
    storeChunk(LB, SB, YB, NCH - 1);
}

extern "C" void kernel_launch(void* const* d_in, const int* in_sizes, int n_in,
                              void* d_out, int out_size, void* d_ws, size_t ws_size,
                              hipStream_t stream) {
    const float* x   = (const float*)d_in[0];
    const float* pla = (const float*)d_in[1];
    const float* plg = (const float*)d_in[2];
    float* out = (float*)d_out;

    dim3 grid(B / 64);   // 128 blocks = 128 full waves (structural max)
    dim3 block(64);      // full wave, 1 row per lane
    hw_kernel<<<grid, block, 0, stream>>>(x, pla, plg, out);
}

// Round 7
// 109.156 us; speedup vs baseline: 2.2265x; 1.3545x over previous
//
#include <hip/hip_runtime.h>
#include <math.h>

// HoltWintersDecomposition: x (8192, 2048) f32, sequential per-row recurrence.
// Producer/consumer wave specialization (AITER-style role split):
//   wave 0 (producer): lane = row, runs the dependent chain, reads x from LDS,
//     writes l/s/y scalars to LDS ([64][65] -> bank (lane+t)%32, 2-way = free).
//   wave 1 (consumer): coalesced global->LDS x prefetch (tile k+1) and
//     LDS->global transposed stores of tile k-1 (full 64B lines, 16 lines/instr
//     instead of 64 partial lines/instr on the per-lane path).
// Double-buffered 64-step tiles, one __syncthreads per tile. The chain wave's
// issue stream is pure VALU + 3 ds_write_b32/step; all TA/vmcnt cost lives on
// the consumer wave, which has ~2x slack per tile.
// Parallel-in-time splice (r6) is mathematically broken here: s ~ 2e-7 ~ 20*EPS
// in this data, EPS breaks the scale invariance -> serial chain is required.

constexpr int   T    = 2048;
constexpr int   B    = 8192;
constexpr int   RPB  = 64;        // rows per block (= producer lanes)
constexpr int   TT   = 64;        // steps per tile
constexpr int   NTI  = T / TT;    // 32 tiles
constexpr int   LSX  = TT + 1;    // 65: LDS stride, bank (row+t)%32, 2-way free
constexpr float EPS  = 1e-8f;

__device__ __forceinline__ float rcp_nr(float d) {
    float r = __builtin_amdgcn_rcpf(d);
    float e = __builtin_fmaf(-d, r, 1.0f);   // e = 1 - d*r
    return __builtin_fmaf(r, e, r);          // ~1 ulp
}

__global__ __launch_bounds__(128, 1)
void hw_kernel(const float* __restrict__ x,
               const float* __restrict__ pla,
               const float* __restrict__ plg,
               float* __restrict__ out)
{
    __shared__ float XT[2][RPB][LSX];
    __shared__ float LT[2][RPB][LSX];
    __shared__ float ST[2][RPB][LSX];
    __shared__ float YT[2][RPB][LSX];

    const int tid  = threadIdx.x;
    const int wid  = tid >> 6;        // 0 = producer, 1 = consumer
    const int lane = tid & 63;
    const int row0 = blockIdx.x * RPB;

    const float alpha = 1.0f / (1.0f + expf(-pla[0]));
    const float gamma = 1.0f / (1.0f + expf(-plg[0]));
    const float oma = 1.0f - alpha, omg = 1.0f - gamma;

    float* __restrict__ lout = out;
    float* __restrict__ sout = out + (size_t)B * T;
    float* __restrict__ yout = out + (size_t)2 * B * T;

    // consumer lane mapping: lane -> (row subgroup, col4)
    const int cr = lane >> 4;          // 0..3
    const int cc = (lane & 15) << 2;   // 0,4,...,60

    float lp = 0.0f, sp = 1.0f;        // producer chain state

    // ---- consumer: coalesced global->LDS x tile load
    auto load_x_tile = [&](int k) {
        const int bsel = k & 1;
        const int t1 = k * TT;
        for (int it = 0; it < 16; ++it) {
            const int r = 4 * it + cr;
            const float4 v = *reinterpret_cast<const float4*>(
                &x[(size_t)(row0 + r) * T + t1 + cc]);
            XT[bsel][r][cc + 0] = v.x;
            XT[bsel][r][cc + 1] = v.y;
            XT[bsel][r][cc + 2] = v.z;
            XT[bsel][r][cc + 3] = v.w;
        }
    };

    // ---- consumer: LDS->global transposed stores (full 64B lines)
    auto store_tile = [&](int m, int itlo, int ithi) {
        const int bsel = m & 1;
        const int t0 = m * TT;
        for (int it = itlo; it < ithi; ++it) {
            const int r = 4 * it + cr;
            const size_t g = (size_t)(row0 + r) * T + t0 + cc;
            float4 vl, vs, vy;
            vl.x = LT[bsel][r][cc + 0]; vl.y = LT[bsel][r][cc + 1];
            vl.z = LT[bsel][r][cc + 2]; vl.w = LT[bsel][r][cc + 3];
            vs.x = ST[bsel][r][cc + 0]; vs.y = ST[bsel][r][cc + 1];
            vs.z = ST[bsel][r][cc + 2]; vs.w = ST[bsel][r][cc + 3];
            vy.x = YT[bsel][r][cc + 0]; vy.y = YT[bsel][r][cc + 1];
            vy.z = YT[bsel][r][cc + 2]; vy.w = YT[bsel][r][cc + 3];
            *reinterpret_cast<float4*>(&lout[g]) = vl;
            *reinterpret_cast<float4*>(&sout[g]) = vs;
            *reinterpret_cast<float4*>(&yout[g]) = vy;
        }
    };

    // ---- producer: one step of the recurrence
    auto do_step = [&](float xt, float& lo, float& so, float& yo) {
        const float rs = rcp_nr(sp + EPS);
        const float lt = __builtin_fmaf(alpha * xt, rs, oma * lp);
        const float rl = rcp_nr(lt + EPS);
        const float st = __builtin_fmaf(gamma * xt, rl, omg * sp);
        yo = xt * __builtin_amdgcn_rcpf(__builtin_fmaf(lt, st, EPS));
        lo = lt; so = st;
        lp = lt; sp = st;
    };

    // ---- producer: compute one 64-step tile from XT into LT/ST/YT
    auto compute_tile = [&](int k, bool first) {
        const int bsel = k & 1;
        #pragma unroll
        for (int g = 0; g < 4; ++g) {
            float xv[16];
            #pragma unroll
            for (int j = 0; j < 16; ++j)
                xv[j] = XT[bsel][lane][16 * g + j];
            #pragma unroll
            for (int j = 0; j < 16; ++j) {
                const int tt = 16 * g + j;
                float lt, st, yt;
                if (g == 0 && j == 0 && first) {
                    // t == 0: l0 = x0, s0 = 1, y0 = x0/(x0 + eps)
                    lt = xv[0]; st = 1.0f;
                    yt = xv[0] * __builtin_amdgcn_rcpf(xv[0] + EPS);
                    lp = lt; sp = st;
                } else {
                    do_step(xv[j], lt, st, yt);
                }
                LT[bsel][lane][tt] = lt;
                ST[bsel][lane][tt] = st;
                YT[bsel][lane][tt] = yt;
            }
        }
    };

    // ---- pipeline
    if (wid == 1) load_x_tile(0);
    __syncthreads();

    for (int k = 0; k < NTI; ++k) {
        if (wid == 0) {
            compute_tile(k, k == 0);
        } else {
            if (k + 1 < NTI) load_x_tile(k + 1);
            if (k > 0)       store_tile(k - 1, 0, 16);
        }
        __syncthreads();
    }

    // final tile: both waves split the store
    store_tile(NTI - 1, wid * 8, wid * 8 + 8);
}

extern "C" void kernel_launch(void* const* d_in, const int* in_sizes, int n_in,
                              void* d_out, int out_size, void* d_ws, size_t ws_size,
                              hipStream_t stream) {
    const float* x   = (const float*)d_in[0];
    const float* pla = (const float*)d_in[1];
    const float* plg = (const float*)d_in[2];
    float* out = (float*)d_out;

    dim3 grid(B / RPB);    // 128 blocks (structural: 8192 rows / 64)
    dim3 block(128);       // wave 0 = producer, wave 1 = consumer
    hw_kernel<<<grid, block, 0, stream>>>(x, pla, plg, out);
}

// Round 8
// 101.667 us; speedup vs baseline: 2.3905x; 1.0737x over previous
//
#include <hip/hip_runtime.h>
#include <math.h>

// HoltWintersDecomposition: x (8192, 2048) f32, sequential per-row recurrence.
// Producer/consumer wave specialization + fully vectorized (b128) LDS traffic.
//   wave 0 (producer): lane = row, dependent chain; reads x as ds_read_b128
//     (4 steps at a time), packs l/s/y in float4 regs, 3x ds_write_b128 per
//     4 steps.
//   wave 1 (consumer): global->LDS x prefetch (float4 -> ds_write_b128) and
//     LDS->global transposed stores (3x ds_read_b128 + 3x full-line float4
//     stores per 4 rows).
// LDS stride 68 words: row base r*272B is 16B-aligned (b128 legal) and start
// bank = (4*lane + off) % 32 -> every 8-lane group covers all 32 banks exactly
// once: conflict-free for all four access patterns.
// DS ops per 64-step tile: 512 scalar (r7) -> 128 b128 (~1536 LDS-pipe cy),
// hidden under the ~3.3K-cy chain.
// Parallel-in-time (r6) is mathematically broken here (s ~ 20*EPS in this
// data; EPS breaks scale invariance) -- the serial chain stands.

constexpr int   T    = 2048;
constexpr int   B    = 8192;
constexpr int   RPB  = 64;        // rows per block (= producer lanes)
constexpr int   TT   = 64;        // steps per tile
constexpr int   NTI  = T / TT;    // 32 tiles
constexpr int   LSX  = 68;        // stride words: 272B rows, 16B aligned, clean banks
constexpr float EPS  = 1e-8f;

__device__ __forceinline__ float rcp_nr(float d) {
    float r = __builtin_amdgcn_rcpf(d);
    float e = __builtin_fmaf(-d, r, 1.0f);   // e = 1 - d*r
    return __builtin_fmaf(r, e, r);          // ~1 ulp
}

__global__ __launch_bounds__(128, 1)
void hw_kernel(const float* __restrict__ x,
               const float* __restrict__ pla,
               const float* __restrict__ plg,
               float* __restrict__ out)
{
    __shared__ alignas(16) float XT[2][RPB][LSX];
    __shared__ alignas(16) float LT[2][RPB][LSX];
    __shared__ alignas(16) float ST[2][RPB][LSX];
    __shared__ alignas(16) float YT[2][RPB][LSX];

    const int tid  = threadIdx.x;
    const int wid  = tid >> 6;        // 0 = producer, 1 = consumer
    const int lane = tid & 63;
    const int row0 = blockIdx.x * RPB;

    const float alpha = 1.0f / (1.0f + expf(-pla[0]));
    const float gamma = 1.0f / (1.0f + expf(-plg[0]));
    const float oma = 1.0f - alpha, omg = 1.0f - gamma;

    float* __restrict__ lout = out;
    float* __restrict__ sout = out + (size_t)B * T;
    float* __restrict__ yout = out + (size_t)2 * B * T;

    // consumer lane mapping: lane -> (row subgroup, col4)
    const int cr = lane >> 4;          // 0..3
    const int cc = (lane & 15) << 2;   // 0,4,...,60

    float lp = 0.0f, sp = 1.0f;        // producer chain state

    // ---- consumer: coalesced global->LDS x tile load (b128 LDS writes)
    auto load_x_tile = [&](int k) {
        const int bsel = k & 1;
        const int t1 = k * TT;
        for (int it = 0; it < 16; ++it) {
            const int r = 4 * it + cr;
            const float4 v = *reinterpret_cast<const float4*>(
                &x[(size_t)(row0 + r) * T + t1 + cc]);
            *reinterpret_cast<float4*>(&XT[bsel][r][cc]) = v;
        }
    };

    // ---- consumer: LDS->global transposed stores (b128 reads, full 64B lines)
    auto store_tile = [&](int m, int itlo, int ithi) {
        const int bsel = m & 1;
        const int t0 = m * TT;
        for (int it = itlo; it < ithi; ++it) {
            const int r = 4 * it + cr;
            const size_t g = (size_t)(row0 + r) * T + t0 + cc;
            const float4 vl = *reinterpret_cast<const float4*>(&LT[bsel][r][cc]);
            const float4 vs = *reinterpret_cast<const float4*>(&ST[bsel][r][cc]);
            const float4 vy = *reinterpret_cast<const float4*>(&YT[bsel][r][cc]);
            *reinterpret_cast<float4*>(&lout[g]) = vl;
            *reinterpret_cast<float4*>(&sout[g]) = vs;
            *reinterpret_cast<float4*>(&yout[g]) = vy;
        }
    };

    // ---- producer: one step of the recurrence
    auto do_step = [&](float xt, float& lo, float& so, float& yo) {
        const float rs = rcp_nr(sp + EPS);
        const float lt = __builtin_fmaf(alpha * xt, rs, oma * lp);
        const float rl = rcp_nr(lt + EPS);
        const float st = __builtin_fmaf(gamma * xt, rl, omg * sp);
        yo = xt * __builtin_amdgcn_rcpf(__builtin_fmaf(lt, st, EPS));
        lo = lt; so = st;
        lp = lt; sp = st;
    };

    // ---- producer: one 64-step tile, 4 steps per b128 group
    auto compute_tile = [&](int k, bool first) {
        const int bsel = k & 1;
        #pragma unroll
        for (int g = 0; g < 16; ++g) {
            const float4 xv = *reinterpret_cast<const float4*>(&XT[bsel][lane][4 * g]);
            float4 lv, sv, yv;
            if (first && g == 0) {
                // t == 0: l0 = x0, s0 = 1, y0 = x0/(x0 + eps)
                lv.x = xv.x; sv.x = 1.0f;
                yv.x = xv.x * __builtin_amdgcn_rcpf(xv.x + EPS);
                lp = xv.x; sp = 1.0f;
                do_step(xv.y, lv.y, sv.y, yv.y);
                do_step(xv.z, lv.z, sv.z, yv.z);
                do_step(xv.w, lv.w, sv.w, yv.w);
            } else {
                do_step(xv.x, lv.x, sv.x, yv.x);
                do_step(xv.y, lv.y, sv.y, yv.y);
                do_step(xv.z, lv.z, sv.z, yv.z);
                do_step(xv.w, lv.w, sv.w, yv.w);
            }
            *reinterpret_cast<float4*>(&LT[bsel][lane][4 * g]) = lv;
            *reinterpret_cast<float4*>(&ST[bsel][lane][4 * g]) = sv;
            *reinterpret_cast<float4*>(&YT[bsel][lane][4 * g]) = yv;
        }
    };

    // ---- pipeline
    if (wid == 1) load_x_tile(0);
    __syncthreads();

    for (int k = 0; k < NTI; ++k) {
        if (wid == 0) {
            compute_tile(k, k == 0);
        } else {
            if (k + 1 < NTI) load_x_tile(k + 1);
            if (k > 0)       store_tile(k - 1, 0, 16);
        }
        __syncthreads();
    }

    // final tile: both waves split the store
    store_tile(NTI - 1, wid * 8, wid * 8 + 8);
}

extern "C" void kernel_launch(void* const* d_in, const int* in_sizes, int n_in,
                              void* d_out, int out_size, void* d_ws, size_t ws_size,
                              hipStream_t stream) {
    const float* x   = (const float*)d_in[0];
    const float* pla = (const float*)d_in[1];
    const float* plg = (const float*)d_in[2];
    float* out = (float*)d_out;

    dim3 grid(B / RPB);    // 128 blocks (structural: 8192 rows / 64)
    dim3 block(128);       // wave 0 = producer, wave 1 = consumer
    hw_kernel<<<grid, block, 0, stream>>>(x, pla, plg, out);
}